// Round 7
// baseline (281.462 us; speedup 1.0000x reference)
//
#include <hip/hip_runtime.h>
#include <hip/hip_bf16.h>

// B=8, T=2048, C=1024, H=64 single-head causal attention. f32 in, f32 out.
// Round 7: barrier-free restructure.
//   transpose_w: W[c][h] f32 -> Wt[mat][h][c] bf16 (1/32 folded into Wq), in d_out.
//   qkv: 256 blocks (one per 64-row tile); MFMA frags loaded DIRECTLY from
//        global (no LDS, no K-loop barriers); writes Q/K/V^T tiles into the
//        block's OWN consumed data region (one barrier before epilogue).
//   attn: 1024 single-wave blocks (16 q-rows each); K/V frags direct from L2;
//        only wave-local P-transpose LDS. No inter-wave barriers.
// Region map: region(rt) = (bf16*)d_in[0] + rt*131072  (= data rows rt*64..+64,
//   256 KB, dead after block rt's K-loop). Q tile [t][h] at +0, K tile [t][h]
//   at +4096, V^T tile [h][t] at +8192 (each 4096 elems).

typedef __bf16 bf16;
typedef __bf16 bf16x8 __attribute__((ext_vector_type(8)));
typedef float f32x4 __attribute__((ext_vector_type(4)));
typedef unsigned int u32;
typedef u32 u32x4 __attribute__((ext_vector_type(4)));

#define T_SZ 2048
#define C_SZ 1024
#define H_SZ 64
#define REGSZ 131072
#define QOFF 0
#define KOFF 4096
#define VOFF 8192
#define PPITCH 72
#define NEG_BIG (-30000.0f)

__device__ __forceinline__ bf16x8 ld8(const bf16* p) { return *(const bf16x8*)p; }

__device__ __forceinline__ bf16x8 cvt8(f32x4 a, f32x4 b) {
  bf16x8 r;
  r[0] = (bf16)a[0]; r[1] = (bf16)a[1]; r[2] = (bf16)a[2]; r[3] = (bf16)a[3];
  r[4] = (bf16)b[0]; r[5] = (bf16)b[1]; r[6] = (bf16)b[2]; r[7] = (bf16)b[3];
  return r;
}

// ---------------------------------------------------------------------------
// Wt[mat][h][c] = W[mat][c][h] (bf16, 1/32 into Wq). grid (16 c-tiles, 3 mats).
__global__ __launch_bounds__(256) void transpose_w(const float* __restrict__ Wq,
                                                   const float* __restrict__ Wk,
                                                   const float* __restrict__ Wv,
                                                   bf16* __restrict__ Wt) {
  __shared__ float sh[64][65];
  int ct = blockIdx.x;
  int mat = blockIdx.y;
  const float* W = (mat == 0) ? Wq : (mat == 1 ? Wk : Wv);
  int tid = threadIdx.x;
  int r = tid >> 2, cb = (tid & 3) * 16;

  const f32x4* src = (const f32x4*)(W + (size_t)(ct * 64 + r) * H_SZ + cb);
#pragma unroll
  for (int v = 0; v < 4; ++v) {
    f32x4 x = src[v];
#pragma unroll
    for (int j = 0; j < 4; ++j) sh[r][cb + v * 4 + j] = x[j];
  }
  __syncthreads();

  float scale = (mat == 0) ? 0.03125f : 1.0f;  // C^-0.5 = 1/32 exact
  bf16x8 o0, o1;
#pragma unroll
  for (int j = 0; j < 8; ++j) o0[j] = (bf16)(sh[cb + j][r] * scale);
#pragma unroll
  for (int j = 0; j < 8; ++j) o1[j] = (bf16)(sh[cb + 8 + j][r] * scale);
  bf16* dst = Wt + ((size_t)mat * H_SZ + r) * C_SZ + ct * 64 + cb;
  *(bf16x8*)dst = o0;
  *(bf16x8*)(dst + 8) = o1;
}

// ---------------------------------------------------------------------------
// QKV: one block per 64-row tile, 4 waves x 16 rows, zero LDS, one barrier.
// data/arena alias (same buffer) -> no __restrict__ on them.
__global__ __launch_bounds__(256) void qkv(const float* data, const bf16* __restrict__ Wt,
                                           bf16* arena) {
  int rt = blockIdx.x;
  int tid = threadIdx.x;
  int w = tid >> 6, lane = tid & 63;
  int l15 = lane & 15, quad = lane >> 4;

  const float* arow = data + (size_t)(rt * 64 + w * 16 + l15) * C_SZ;

  f32x4 acc[3][4];
  f32x4 zero = {0.f, 0.f, 0.f, 0.f};
#pragma unroll
  for (int mat = 0; mat < 3; ++mat)
#pragma unroll
    for (int nt = 0; nt < 4; ++nt) acc[mat][nt] = zero;

  for (int kc = 0; kc < C_SZ; kc += 64) {
    bf16x8 af[2];
#pragma unroll
    for (int kh = 0; kh < 2; ++kh) {
      const f32x4* p = (const f32x4*)(arow + kc + kh * 32 + quad * 8);
      af[kh] = cvt8(p[0], p[1]);
    }
#pragma unroll
    for (int mat = 0; mat < 3; ++mat) {
#pragma unroll
      for (int nt = 0; nt < 4; ++nt) {
        const bf16* wrow = Wt + ((size_t)mat * H_SZ + nt * 16 + l15) * C_SZ + kc + quad * 8;
        acc[mat][nt] = __builtin_amdgcn_mfma_f32_16x16x32_bf16(af[0], ld8(wrow), acc[mat][nt], 0, 0, 0);
        acc[mat][nt] = __builtin_amdgcn_mfma_f32_16x16x32_bf16(af[1], ld8(wrow + 32), acc[mat][nt], 0, 0, 0);
      }
    }
  }

  __syncthreads();  // ALL waves' data reads drained before overwriting the region

  bf16* reg = arena + (size_t)rt * REGSZ;
#pragma unroll
  for (int nt = 0; nt < 4; ++nt) {
#pragma unroll
    for (int r = 0; r < 4; ++r) {
      int tloc = w * 16 + quad * 4 + r;
      int h = nt * 16 + l15;
      reg[QOFF + tloc * H_SZ + h] = (bf16)acc[0][nt][r];
      reg[KOFF + tloc * H_SZ + h] = (bf16)acc[1][nt][r];
      reg[VOFF + h * H_SZ + tloc] = (bf16)acc[2][nt][r];  // V^T tile [h][t]
    }
  }
}

// ---------------------------------------------------------------------------
// Flash attention: 1 wave per 16-row q-tile. grid (128, 8), block 64.
__global__ __launch_bounds__(64) void attn(const bf16* __restrict__ arena,
                                           float* __restrict__ out) {
  __shared__ bf16 Ps[16 * PPITCH];
  int qt = blockIdx.x;  // 0..127
  int b = blockIdx.y;   // 0..7
  int lane = threadIdx.x;
  int l15 = lane & 15, quad = lane >> 4;

  const bf16* base = arena + (size_t)b * 32 * REGSZ;
  const bf16* qp = base + (size_t)(qt >> 2) * REGSZ + QOFF + ((qt & 3) * 16 + l15) * H_SZ;
  bf16x8 qf0 = ld8(qp + quad * 8);
  bf16x8 qf1 = ld8(qp + 32 + quad * 8);

  f32x4 accO[4];
  f32x4 zero = {0.f, 0.f, 0.f, 0.f};
#pragma unroll
  for (int nt = 0; nt < 4; ++nt) accO[nt] = zero;
  float m[4], l[4];
#pragma unroll
  for (int r = 0; r < 4; ++r) { m[r] = NEG_BIG; l[r] = 0.f; }

  int qrow_base = qt * 16 + quad * 4;
  int ktmax = qt >> 2;

  for (int kt = 0; kt <= ktmax; ++kt) {
    const bf16* reg = base + (size_t)kt * REGSZ;

    f32x4 s[4];
#pragma unroll
    for (int nt = 0; nt < 4; ++nt) s[nt] = zero;
#pragma unroll
    for (int nt = 0; nt < 4; ++nt) {
      const bf16* kr = reg + KOFF + (nt * 16 + l15) * H_SZ + quad * 8;
      s[nt] = __builtin_amdgcn_mfma_f32_16x16x32_bf16(qf0, ld8(kr), s[nt], 0, 0, 0);
      s[nt] = __builtin_amdgcn_mfma_f32_16x16x32_bf16(qf1, ld8(kr + 32), s[nt], 0, 0, 0);
    }

    if (kt == ktmax) {  // diagonal tile: causal mask
#pragma unroll
      for (int nt = 0; nt < 4; ++nt) {
        int colg = kt * 64 + nt * 16 + l15;
#pragma unroll
        for (int r = 0; r < 4; ++r)
          if (colg > qrow_base + r) s[nt][r] = NEG_BIG;
      }
    }

    float mx[4];
#pragma unroll
    for (int r = 0; r < 4; ++r)
      mx[r] = fmaxf(fmaxf(s[0][r], s[1][r]), fmaxf(s[2][r], s[3][r]));
#pragma unroll
    for (int off = 1; off <= 8; off <<= 1) {
#pragma unroll
      for (int r = 0; r < 4; ++r) mx[r] = fmaxf(mx[r], __shfl_xor(mx[r], off));
    }

    float alpha[4];
#pragma unroll
    for (int r = 0; r < 4; ++r) {
      float mnew = fmaxf(m[r], mx[r]);
      alpha[r] = __expf(m[r] - mnew);  // args <= 0 by construction
      m[r] = mnew;
    }

    float rs[4] = {0.f, 0.f, 0.f, 0.f};
#pragma unroll
    for (int nt = 0; nt < 4; ++nt) {
#pragma unroll
      for (int r = 0; r < 4; ++r) {
        float p = __expf(s[nt][r] - m[r]);
        s[nt][r] = p;
        rs[r] += p;
      }
    }
#pragma unroll
    for (int off = 1; off <= 8; off <<= 1) {
#pragma unroll
      for (int r = 0; r < 4; ++r) rs[r] += __shfl_xor(rs[r], off);
    }
#pragma unroll
    for (int r = 0; r < 4; ++r) l[r] = l[r] * alpha[r] + rs[r];

    __syncthreads();  // prior iter's Ps reads done (1-wave: lgkm drain)
#pragma unroll
    for (int nt = 0; nt < 4; ++nt) {
#pragma unroll
      for (int r = 0; r < 4; ++r)
        Ps[(quad * 4 + r) * PPITCH + nt * 16 + l15] = (bf16)s[nt][r];
    }
    __syncthreads();  // Ps writes visible

#pragma unroll
    for (int nt = 0; nt < 4; ++nt) {
#pragma unroll
      for (int r = 0; r < 4; ++r) accO[nt][r] *= alpha[r];
    }
#pragma unroll
    for (int kh = 0; kh < 2; ++kh) {
      bf16x8 pf = ld8((const bf16*)Ps + l15 * PPITCH + kh * 32 + quad * 8);
#pragma unroll
      for (int nt = 0; nt < 4; ++nt) {
        bf16x8 vf = ld8(reg + VOFF + (nt * 16 + l15) * H_SZ + kh * 32 + quad * 8);
        accO[nt] = __builtin_amdgcn_mfma_f32_16x16x32_bf16(pf, vf, accO[nt], 0, 0, 0);
      }
    }
  }

  float inv[4];
#pragma unroll
  for (int r = 0; r < 4; ++r) inv[r] = 1.f / l[r];  // l >= 1 guaranteed
#pragma unroll
  for (int nt = 0; nt < 4; ++nt) {
#pragma unroll
    for (int r = 0; r < 4; ++r) {
      int t = qt * 16 + quad * 4 + r;
      int h = nt * 16 + l15;
      out[((size_t)b * T_SZ + t) * H_SZ + h] = accO[nt][r] * inv[r];
    }
  }
}

// ---------------------------------------------------------------------------
extern "C" void kernel_launch(void* const* d_in, const int* in_sizes, int n_in,
                              void* d_out, int out_size, void* d_ws, size_t ws_size,
                              hipStream_t stream) {
  const float* data = (const float*)d_in[0];
  bf16* arena = (bf16*)d_in[0];       // per-tile QKV regions over consumed input
  bf16* Wt = (bf16*)d_out;            // 384 KB in d_out; dead before attn writes

  transpose_w<<<dim3(16, 3), 256, 0, stream>>>((const float*)d_in[1],
                                               (const float*)d_in[2],
                                               (const float*)d_in[3], Wt);
  qkv<<<256, 256, 0, stream>>>(data, Wt, arena);
  attn<<<dim3(128, 8), 64, 0, stream>>>(arena, (float*)d_out);
}

// Round 8
// 204.658 us; speedup vs baseline: 1.3753x; 1.3753x over previous
//
#include <hip/hip_runtime.h>
#include <hip/hip_bf16.h>

// B=8, T=2048, C=1024, H=64 single-head causal attention. f32 in, f32 out.
// Round 8: DPP softmax (kills ~1000cyc shuffle chains), exp2-domain scores
// (log2e/32 folded into Wq), 8-wave/CU qkv (1024 blocks x 2 waves, no LDS),
// attn 4-wave blocks with LDS K/V staging and 2 barriers/tile.
// Region map: region rt (0..1023) = 16 token rows = bf16[rt*32768 .. +3072)
//   inside the same rows' consumed f32 input bytes. Q[t][h]@0, K[t][h]@1024,
//   V^T[h][t16]@2048.

typedef __bf16 bf16;
typedef __bf16 bf16x8 __attribute__((ext_vector_type(8)));
typedef float f32x4 __attribute__((ext_vector_type(4)));
typedef unsigned int u32;
typedef u32 u32x4 __attribute__((ext_vector_type(4)));

#define T_SZ 2048
#define C_SZ 1024
#define H_SZ 64
#define REGSZ 32768
#define QOFF 0
#define KOFF 1024
#define VOFF 2048
#define PPITCH 72
#define NEG_BIG (-30000.0f)
#define QSCALE 0.04508422f  // (1/32) * log2(e): softmax done in exp2 domain

__device__ __forceinline__ bf16x8 ld8(const bf16* p) { return *(const bf16x8*)p; }

__device__ __forceinline__ bf16x8 cvt8(f32x4 a, f32x4 b) {
  bf16x8 r;
  r[0] = (bf16)a[0]; r[1] = (bf16)a[1]; r[2] = (bf16)a[2]; r[3] = (bf16)a[3];
  r[4] = (bf16)b[0]; r[5] = (bf16)b[1]; r[6] = (bf16)b[2]; r[7] = (bf16)b[3];
  return r;
}

// DPP rotate within 16-lane row (= quad group). ROW_ROR:n = 0x120|n.
template <int CTRL>
__device__ __forceinline__ float dpp_mov(float x) {
  return __builtin_bit_cast(float,
      __builtin_amdgcn_update_dpp(0, __builtin_bit_cast(int, x), CTRL, 0xf, 0xf, true));
}
__device__ __forceinline__ float qmax16(float x) {
  x = fmaxf(x, dpp_mov<0x121>(x));
  x = fmaxf(x, dpp_mov<0x122>(x));
  x = fmaxf(x, dpp_mov<0x124>(x));
  x = fmaxf(x, dpp_mov<0x128>(x));
  return x;
}
__device__ __forceinline__ float qsum16(float x) {
  x += dpp_mov<0x121>(x);
  x += dpp_mov<0x122>(x);
  x += dpp_mov<0x124>(x);
  x += dpp_mov<0x128>(x);
  return x;
}

// ---------------------------------------------------------------------------
// Wt[mat][h][c] = W[mat][c][h] (bf16); QSCALE folded into Wq.
__global__ __launch_bounds__(256) void transpose_w(const float* __restrict__ Wq,
                                                   const float* __restrict__ Wk,
                                                   const float* __restrict__ Wv,
                                                   bf16* __restrict__ Wt) {
  __shared__ float sh[64][65];
  int ct = blockIdx.x;
  int mat = blockIdx.y;
  const float* W = (mat == 0) ? Wq : (mat == 1 ? Wk : Wv);
  int tid = threadIdx.x;
  int r = tid >> 2, cb = (tid & 3) * 16;

  const f32x4* src = (const f32x4*)(W + (size_t)(ct * 64 + r) * H_SZ + cb);
#pragma unroll
  for (int v = 0; v < 4; ++v) {
    f32x4 x = src[v];
#pragma unroll
    for (int j = 0; j < 4; ++j) sh[r][cb + v * 4 + j] = x[j];
  }
  __syncthreads();

  float scale = (mat == 0) ? QSCALE : 1.0f;
  bf16x8 o0, o1;
#pragma unroll
  for (int j = 0; j < 8; ++j) o0[j] = (bf16)(sh[cb + j][r] * scale);
#pragma unroll
  for (int j = 0; j < 8; ++j) o1[j] = (bf16)(sh[cb + 8 + j][r] * scale);
  bf16* dst = Wt + ((size_t)mat * H_SZ + r) * C_SZ + ct * 64 + cb;
  *(bf16x8*)dst = o0;
  *(bf16x8*)(dst + 8) = o1;
}

// ---------------------------------------------------------------------------
// QKV: 1024 blocks (one 16-row region each) x 128 thr (2 waves split 192 cols).
// A frags direct from global (16 full cache lines / frag load); B from L2 Wt.
// data/arena alias -> no __restrict__.
__global__ __launch_bounds__(128) void qkv(const float* data, const bf16* __restrict__ Wt,
                                           bf16* arena) {
  int rt = blockIdx.x;            // 16-row region index
  int w = threadIdx.x >> 6;       // 0..1: output-column half
  int lane = threadIdx.x & 63;
  int l15 = lane & 15, quad = lane >> 4;

  const float* arow = data + ((size_t)rt * 16 + l15) * C_SZ;

  f32x4 acc[6];
  f32x4 zero = {0.f, 0.f, 0.f, 0.f};
#pragma unroll
  for (int n = 0; n < 6; ++n) acc[n] = zero;

#pragma unroll 4
  for (int kc = 0; kc < C_SZ; kc += 32) {
    const f32x4* p = (const f32x4*)(arow + kc + quad * 8);
    bf16x8 af = cvt8(p[0], p[1]);
#pragma unroll
    for (int n = 0; n < 6; ++n) {
      const bf16* wr = Wt + (size_t)(w * 96 + n * 16 + l15) * C_SZ + kc + quad * 8;
      acc[n] = __builtin_amdgcn_mfma_f32_16x16x32_bf16(af, ld8(wr), acc[n], 0, 0, 0);
    }
  }

  __syncthreads();  // both waves' reads of this region drained (vmcnt+barrier)

  bf16* reg = arena + (size_t)rt * REGSZ;
#pragma unroll
  for (int n = 0; n < 6; ++n) {
    int col = w * 96 + n * 16 + l15;  // 0..191
    int mat = col >> 6, h = col & 63;
#pragma unroll
    for (int r = 0; r < 4; ++r) {
      int t = quad * 4 + r;           // t-local 0..15
      bf16 val = (bf16)acc[n][r];
      if (mat == 0) reg[QOFF + t * 64 + h] = val;
      else if (mat == 1) reg[KOFF + t * 64 + h] = val;
      else reg[VOFF + h * 16 + t] = val;  // V^T [h][t16]
    }
  }
}

// ---------------------------------------------------------------------------
// Flash attention: block=(qt 0..31, b 0..7), 4 waves x 16 q-rows, LDS K/V.
__global__ __launch_bounds__(256) void attn(const bf16* __restrict__ arena,
                                            float* __restrict__ out) {
  __shared__ bf16 Ks[64 * PPITCH];
  __shared__ bf16 Vs[64 * PPITCH];   // [h][key0..63]
  __shared__ bf16 Ps[4][16 * PPITCH];

  int qt = blockIdx.x;
  int b = blockIdx.y;
  int tid = threadIdx.x;
  int w = tid >> 6, lane = tid & 63;
  int l15 = lane & 15, quad = lane >> 4;

  const bf16* base = arena + (size_t)b * 128 * REGSZ;

  // Q fragments direct from global (one region per wave)
  const bf16* qreg = base + (size_t)(qt * 4 + w) * REGSZ + QOFF + l15 * 64;
  bf16x8 qf0 = ld8(qreg + quad * 8);
  bf16x8 qf1 = ld8(qreg + 32 + quad * 8);

  f32x4 accO[4];
  f32x4 zero = {0.f, 0.f, 0.f, 0.f};
#pragma unroll
  for (int nt = 0; nt < 4; ++nt) accO[nt] = zero;
  float m[4], l[4];
#pragma unroll
  for (int r = 0; r < 4; ++r) { m[r] = NEG_BIG; l[r] = 0.f; }

  int qrow_base = qt * 64 + w * 16 + quad * 4;
  int sr = tid >> 2, sc4 = tid & 3;  // staging coords

  for (int kt = 0; kt <= qt; ++kt) {
    __syncthreads();  // prior iter's Ks/Vs reads drained
    {  // stage K tile [key][h] and V^T tile [h][key] from 4 regions
      const bf16* kreg = base + (size_t)(kt * 4 + (sr >> 4)) * REGSZ + KOFF + (sr & 15) * 64 + sc4 * 16;
      u32x4 k0 = *(const u32x4*)kreg;
      u32x4 k1 = *(const u32x4*)(kreg + 8);
      const bf16* vreg = base + (size_t)(kt * 4 + sc4) * REGSZ + VOFF + sr * 16;
      u32x4 v0 = *(const u32x4*)vreg;
      u32x4 v1 = *(const u32x4*)(vreg + 8);
      *(u32x4*)(Ks + sr * PPITCH + sc4 * 16) = k0;
      *(u32x4*)(Ks + sr * PPITCH + sc4 * 16 + 8) = k1;
      *(u32x4*)(Vs + sr * PPITCH + sc4 * 16) = v0;
      *(u32x4*)(Vs + sr * PPITCH + sc4 * 16 + 8) = v1;
    }
    __syncthreads();

    // S = Q K^T (exp2 domain; scale pre-folded into Q)
    f32x4 s[4];
#pragma unroll
    for (int nt = 0; nt < 4; ++nt) s[nt] = zero;
#pragma unroll
    for (int nt = 0; nt < 4; ++nt) {
      const bf16* kr = Ks + (nt * 16 + l15) * PPITCH + quad * 8;
      s[nt] = __builtin_amdgcn_mfma_f32_16x16x32_bf16(qf0, ld8(kr), s[nt], 0, 0, 0);
      s[nt] = __builtin_amdgcn_mfma_f32_16x16x32_bf16(qf1, ld8(kr + 32), s[nt], 0, 0, 0);
    }

    if (kt == qt) {  // causal mask on diagonal tile
#pragma unroll
      for (int nt = 0; nt < 4; ++nt) {
        int colg = kt * 64 + nt * 16 + l15;
#pragma unroll
        for (int r = 0; r < 4; ++r)
          if (colg > qrow_base + r) s[nt][r] = NEG_BIG;
      }
    }

    // row max via DPP (16-lane rotate chains, ~40cyc vs ~500 for shfl)
    float alpha[4];
#pragma unroll
    for (int r = 0; r < 4; ++r) {
      float mx = qmax16(fmaxf(fmaxf(s[0][r], s[1][r]), fmaxf(s[2][r], s[3][r])));
      float mnew = fmaxf(m[r], mx);
      alpha[r] = exp2f(m[r] - mnew);
      m[r] = mnew;
    }

    float rs[4];
#pragma unroll
    for (int r = 0; r < 4; ++r) rs[r] = 0.f;
#pragma unroll
    for (int nt = 0; nt < 4; ++nt) {
#pragma unroll
      for (int r = 0; r < 4; ++r) {
        float p = exp2f(s[nt][r] - m[r]);
        s[nt][r] = p;
        rs[r] += p;
      }
    }
#pragma unroll
    for (int r = 0; r < 4; ++r) l[r] = l[r] * alpha[r] + qsum16(rs[r]);

    // P: C/D layout -> per-wave LDS -> A layout (wave-local; lgkm-ordered)
#pragma unroll
    for (int nt = 0; nt < 4; ++nt) {
#pragma unroll
      for (int r = 0; r < 4; ++r)
        Ps[w][(quad * 4 + r) * PPITCH + nt * 16 + l15] = (bf16)s[nt][r];
    }

#pragma unroll
    for (int nt = 0; nt < 4; ++nt) {
#pragma unroll
      for (int r = 0; r < 4; ++r) accO[nt][r] *= alpha[r];
    }
#pragma unroll
    for (int kh = 0; kh < 2; ++kh) {
      bf16x8 pf = ld8((const bf16*)Ps[w] + l15 * PPITCH + kh * 32 + quad * 8);
#pragma unroll
      for (int nt = 0; nt < 4; ++nt) {
        bf16x8 vf = ld8(Vs + (nt * 16 + l15) * PPITCH + kh * 32 + quad * 8);
        accO[nt] = __builtin_amdgcn_mfma_f32_16x16x32_bf16(pf, vf, accO[nt], 0, 0, 0);
      }
    }
  }

  float inv[4];
#pragma unroll
  for (int r = 0; r < 4; ++r) inv[r] = 1.f / l[r];  // l >= 1 by construction
#pragma unroll
  for (int nt = 0; nt < 4; ++nt) {
#pragma unroll
    for (int r = 0; r < 4; ++r) {
      int t = qt * 64 + w * 16 + quad * 4 + r;
      int h = nt * 16 + l15;
      out[((size_t)b * T_SZ + t) * H_SZ + h] = accO[nt][r] * inv[r];
    }
  }
}

// ---------------------------------------------------------------------------
extern "C" void kernel_launch(void* const* d_in, const int* in_sizes, int n_in,
                              void* d_out, int out_size, void* d_ws, size_t ws_size,
                              hipStream_t stream) {
  const float* data = (const float*)d_in[0];
  bf16* arena = (bf16*)d_in[0];   // per-region QKV over consumed input rows
  bf16* Wt = (bf16*)d_out;        // 384 KB staging; dead before attn overwrites

  transpose_w<<<dim3(16, 3), 256, 0, stream>>>((const float*)d_in[1],
                                               (const float*)d_in[2],
                                               (const float*)d_in[3], Wt);
  qkv<<<1024, 128, 0, stream>>>(data, Wt, arena);
  attn<<<dim3(32, 8), 256, 0, stream>>>(arena, (float*)d_out);
}

// Round 9
// 184.934 us; speedup vs baseline: 1.5220x; 1.1067x over previous
//
#include <hip/hip_runtime.h>
#include <hip/hip_bf16.h>

// B=8, T=2048, C=1024, H=64 single-head causal attention. f32 in, f32 out.
// Round 9: qkv = LDS-staged A panel (bulk HBM streaming) + operand-swapped
// MFMA epilogues (all packed 8B stores). attn = barrier-free 4-wave blocks,
// K/V fragments direct from L2 with software prefetch, DPP softmax in exp2
// domain (log2e/32 folded into Wq).
// Region map: region rt (0..1023) = 16 token rows, bf16[rt*32768 ..) inside
// those rows' consumed f32 input bytes. Q[t][h]@0, K[t][h]@1024, V^T[h][t16]@2048.

typedef __bf16 bf16;
typedef __bf16 bf16x8 __attribute__((ext_vector_type(8)));
typedef float f32x4 __attribute__((ext_vector_type(4)));
typedef unsigned int u32;
typedef u32 u32x2 __attribute__((ext_vector_type(2)));
typedef u32 u32x4 __attribute__((ext_vector_type(4)));

#define T_SZ 2048
#define C_SZ 1024
#define H_SZ 64
#define REGSZ 32768
#define QOFF 0
#define KOFF 1024
#define VOFF 2048
#define PPITCH 72
#define APITCH 1032   // 1024+8: rows 16B-aligned (2064B=129*16); b128 bank-uniform
#define NEG_BIG (-30000.0f)
#define QSCALE 0.04508422f  // (1/32) * log2(e)

__device__ __forceinline__ bf16x8 ld8(const bf16* p) { return *(const bf16x8*)p; }

// DPP rotate within 16-lane row. ROW_ROR:n = 0x120|n.
template <int CTRL>
__device__ __forceinline__ float dpp_mov(float x) {
  return __builtin_bit_cast(float,
      __builtin_amdgcn_update_dpp(0, __builtin_bit_cast(int, x), CTRL, 0xf, 0xf, true));
}
__device__ __forceinline__ float qmax16(float x) {
  x = fmaxf(x, dpp_mov<0x121>(x));
  x = fmaxf(x, dpp_mov<0x122>(x));
  x = fmaxf(x, dpp_mov<0x124>(x));
  x = fmaxf(x, dpp_mov<0x128>(x));
  return x;
}
__device__ __forceinline__ float qsum16(float x) {
  x += dpp_mov<0x121>(x);
  x += dpp_mov<0x122>(x);
  x += dpp_mov<0x124>(x);
  x += dpp_mov<0x128>(x);
  return x;
}

// ---------------------------------------------------------------------------
// Wt[mat][h][c] = W[mat][c][h] (bf16); QSCALE folded into Wq.
__global__ __launch_bounds__(256) void transpose_w(const float* __restrict__ Wq,
                                                   const float* __restrict__ Wk,
                                                   const float* __restrict__ Wv,
                                                   bf16* __restrict__ Wt) {
  __shared__ float sh[64][65];
  int ct = blockIdx.x;
  int mat = blockIdx.y;
  const float* W = (mat == 0) ? Wq : (mat == 1 ? Wk : Wv);
  int tid = threadIdx.x;
  int r = tid >> 2, cb = (tid & 3) * 16;

  const f32x4* src = (const f32x4*)(W + (size_t)(ct * 64 + r) * H_SZ + cb);
#pragma unroll
  for (int v = 0; v < 4; ++v) {
    f32x4 x = src[v];
#pragma unroll
    for (int j = 0; j < 4; ++j) sh[r][cb + v * 4 + j] = x[j];
  }
  __syncthreads();

  float scale = (mat == 0) ? QSCALE : 1.0f;
  bf16x8 o0, o1;
#pragma unroll
  for (int j = 0; j < 8; ++j) o0[j] = (bf16)(sh[cb + j][r] * scale);
#pragma unroll
  for (int j = 0; j < 8; ++j) o1[j] = (bf16)(sh[cb + 8 + j][r] * scale);
  bf16* dst = Wt + ((size_t)mat * H_SZ + r) * C_SZ + ct * 64 + cb;
  *(bf16x8*)dst = o0;
  *(bf16x8*)(dst + 8) = o1;
}

// ---------------------------------------------------------------------------
// QKV: 1024 blocks x 128 thr (2 waves split 192 output cols), 4 blocks/CU.
// Phase 1: burst-stage 16x1024 f32 -> bf16 LDS (32 indep loads/thread).
// Phase 2: 32 K-iters from LDS + L2 Wt. Operand order picks D layout:
//   Q/K: mfma(Wfrag, datafrag) -> D[h][t] per-lane 4 consecutive h (fixed t)
//   V  : mfma(datafrag, Wfrag) -> D[t][h] per-lane 4 consecutive t (fixed h)
// -> every epilogue store is a packed 8B store. data/arena alias.
__global__ __launch_bounds__(128, 2) void qkv(const float* data, const bf16* __restrict__ Wt,
                                              bf16* arena) {
  __shared__ bf16 As[16 * APITCH];
  int rt = blockIdx.x;
  int tid = threadIdx.x;
  int w = tid >> 6, lane = tid & 63;
  int l15 = lane & 15, quad = lane >> 4;

  const float* src = data + (size_t)rt * 16 * C_SZ;
#pragma unroll
  for (int seg = 0; seg < 32; ++seg) {
    int u = seg * 128 + tid;       // f32x4 unit id
    int row = u >> 8, c4 = u & 255;
    f32x4 x = *(const f32x4*)(src + (size_t)row * C_SZ + c4 * 4);
    bf16 t4[4] = {(bf16)x[0], (bf16)x[1], (bf16)x[2], (bf16)x[3]};
    *(u32x2*)(As + row * APITCH + c4 * 4) = *(const u32x2*)t4;
  }
  __syncthreads();  // region f32 fully consumed; LDS visible

  f32x4 acc[6];
  f32x4 zero = {0.f, 0.f, 0.f, 0.f};
#pragma unroll
  for (int j = 0; j < 6; ++j) acc[j] = zero;

#pragma unroll 2
  for (int kc = 0; kc < C_SZ; kc += 32) {
    bf16x8 df = ld8(As + l15 * APITCH + kc + quad * 8);
#pragma unroll
    for (int j = 0; j < 6; ++j) {
      int colb = w * 96 + j * 16;
      bf16x8 wf = ld8(Wt + (size_t)(colb + l15) * C_SZ + kc + quad * 8);
      if (colb < 128)  // Q/K: swapped operands -> D[h][t]
        acc[j] = __builtin_amdgcn_mfma_f32_16x16x32_bf16(wf, df, acc[j], 0, 0, 0);
      else             // V: D[t][h]
        acc[j] = __builtin_amdgcn_mfma_f32_16x16x32_bf16(df, wf, acc[j], 0, 0, 0);
    }
  }

  bf16* reg = arena + (size_t)rt * REGSZ;
#pragma unroll
  for (int j = 0; j < 6; ++j) {
    int colb = w * 96 + j * 16;
    bf16 p4[4] = {(bf16)acc[j][0], (bf16)acc[j][1], (bf16)acc[j][2], (bf16)acc[j][3]};
    if (colb < 128) {
      int mat = colb >> 6;                  // 0=Q, 1=K (chunks are 16-aligned)
      int h = (colb & 63) + quad * 4;       // 4 consecutive h
      bf16* dst = reg + (mat == 0 ? QOFF : KOFF) + l15 * 64 + h;
      *(u32x2*)dst = *(const u32x2*)p4;
    } else {
      int h = (colb - 128) + l15;           // V^T [h][t16], 4 consecutive t
      bf16* dst = reg + VOFF + h * 16 + quad * 4;
      *(u32x2*)dst = *(const u32x2*)p4;
    }
  }
}

// ---------------------------------------------------------------------------
// Flash attention: block=(qt 0..31, b 0..7), 4 independent waves (16 q-rows
// each), ZERO barriers. K/V fragments direct from global (L2); next-tile K
// prefetched; V loaded before softmax. P-transpose via per-wave LDS slice.
__global__ __launch_bounds__(256) void attn(const bf16* __restrict__ arena,
                                            float* __restrict__ out) {
  __shared__ bf16 Ps[4][16 * PPITCH];
  int qt = blockIdx.x;
  int b = blockIdx.y;
  int tid = threadIdx.x;
  int w = tid >> 6, lane = tid & 63;
  int l15 = lane & 15, quad = lane >> 4;

  const bf16* base = arena + (size_t)b * 128 * REGSZ;

  const bf16* qreg = base + (size_t)(qt * 4 + w) * REGSZ + QOFF + l15 * 64;
  bf16x8 qf0 = ld8(qreg + quad * 8);
  bf16x8 qf1 = ld8(qreg + 32 + quad * 8);

  f32x4 accO[4];
  f32x4 zero = {0.f, 0.f, 0.f, 0.f};
#pragma unroll
  for (int nt = 0; nt < 4; ++nt) accO[nt] = zero;
  float m[4], l[4];
#pragma unroll
  for (int r = 0; r < 4; ++r) { m[r] = NEG_BIG; l[r] = 0.f; }

  int qrow_base = qt * 64 + w * 16 + quad * 4;
  int vro = (quad >> 1);                 // V region sub-index
  int vco = (quad & 1) * 8;              // V in-row offset

  bf16x8 kf[8];
#pragma unroll
  for (int nt = 0; nt < 4; ++nt) {       // preload K for kt=0
    const bf16* kp = base + (size_t)nt * REGSZ + KOFF + l15 * 64 + quad * 8;
    kf[2 * nt] = ld8(kp);
    kf[2 * nt + 1] = ld8(kp + 32);
  }

  for (int kt = 0; kt <= qt; ++kt) {
    // V for this tile (issue early; consumed after softmax)
    bf16x8 vf[8];
#pragma unroll
    for (int kh = 0; kh < 2; ++kh) {
#pragma unroll
      for (int nt = 0; nt < 4; ++nt) {
        const bf16* vp = base + (size_t)(kt * 4 + kh * 2 + vro) * REGSZ + VOFF +
                         (nt * 16 + l15) * 16 + vco;
        vf[kh * 4 + nt] = ld8(vp);
      }
    }
    // prefetch next K tile
    bf16x8 kn[8];
    if (kt < qt) {
#pragma unroll
      for (int nt = 0; nt < 4; ++nt) {
        const bf16* kp = base + (size_t)((kt + 1) * 4 + nt) * REGSZ + KOFF + l15 * 64 + quad * 8;
        kn[2 * nt] = ld8(kp);
        kn[2 * nt + 1] = ld8(kp + 32);
      }
    }

    f32x4 s[4];
#pragma unroll
    for (int nt = 0; nt < 4; ++nt) s[nt] = zero;
#pragma unroll
    for (int nt = 0; nt < 4; ++nt) {
      s[nt] = __builtin_amdgcn_mfma_f32_16x16x32_bf16(qf0, kf[2 * nt], s[nt], 0, 0, 0);
      s[nt] = __builtin_amdgcn_mfma_f32_16x16x32_bf16(qf1, kf[2 * nt + 1], s[nt], 0, 0, 0);
    }

    if (kt == qt) {  // causal mask on diagonal tile
#pragma unroll
      for (int nt = 0; nt < 4; ++nt) {
        int colg = kt * 64 + nt * 16 + l15;
#pragma unroll
        for (int r = 0; r < 4; ++r)
          if (colg > qrow_base + r) s[nt][r] = NEG_BIG;
      }
    }

    float alpha[4];
#pragma unroll
    for (int r = 0; r < 4; ++r) {
      float mx = qmax16(fmaxf(fmaxf(s[0][r], s[1][r]), fmaxf(s[2][r], s[3][r])));
      float mnew = fmaxf(m[r], mx);
      alpha[r] = exp2f(m[r] - mnew);
      m[r] = mnew;
    }

    float rs[4] = {0.f, 0.f, 0.f, 0.f};
#pragma unroll
    for (int nt = 0; nt < 4; ++nt) {
#pragma unroll
      for (int r = 0; r < 4; ++r) {
        float p = exp2f(s[nt][r] - m[r]);
        s[nt][r] = p;
        rs[r] += p;
      }
    }
#pragma unroll
    for (int r = 0; r < 4; ++r) l[r] = l[r] * alpha[r] + qsum16(rs[r]);

    // P: C/D layout -> per-wave LDS -> A layout (same-wave RAW, lgkm-ordered)
#pragma unroll
    for (int nt = 0; nt < 4; ++nt) {
#pragma unroll
      for (int r = 0; r < 4; ++r)
        Ps[w][(quad * 4 + r) * PPITCH + nt * 16 + l15] = (bf16)s[nt][r];
    }

#pragma unroll
    for (int nt = 0; nt < 4; ++nt) {
#pragma unroll
      for (int r = 0; r < 4; ++r) accO[nt][r] *= alpha[r];
    }
    bf16x8 pf0 = ld8((const bf16*)Ps[w] + l15 * PPITCH + quad * 8);
    bf16x8 pf1 = ld8((const bf16*)Ps[w] + l15 * PPITCH + 32 + quad * 8);
#pragma unroll
    for (int nt = 0; nt < 4; ++nt) {
      accO[nt] = __builtin_amdgcn_mfma_f32_16x16x32_bf16(pf0, vf[nt], accO[nt], 0, 0, 0);
      accO[nt] = __builtin_amdgcn_mfma_f32_16x16x32_bf16(pf1, vf[4 + nt], accO[nt], 0, 0, 0);
    }

#pragma unroll
    for (int i = 0; i < 8; ++i) kf[i] = kn[i];
  }

  float inv[4];
#pragma unroll
  for (int r = 0; r < 4; ++r) inv[r] = 1.f / l[r];
#pragma unroll
  for (int nt = 0; nt < 4; ++nt) {
#pragma unroll
    for (int r = 0; r < 4; ++r) {
      int t = qt * 64 + w * 16 + quad * 4 + r;
      int h = nt * 16 + l15;
      out[((size_t)b * T_SZ + t) * H_SZ + h] = accO[nt][r] * inv[r];
    }
  }
}

// ---------------------------------------------------------------------------
extern "C" void kernel_launch(void* const* d_in, const int* in_sizes, int n_in,
                              void* d_out, int out_size, void* d_ws, size_t ws_size,
                              hipStream_t stream) {
  const float* data = (const float*)d_in[0];
  bf16* arena = (bf16*)d_in[0];   // per-region QKV over consumed input rows
  bf16* Wt = (bf16*)d_out;        // 384 KB staging; dead before attn overwrites

  transpose_w<<<dim3(16, 3), 256, 0, stream>>>((const float*)d_in[1],
                                               (const float*)d_in[2],
                                               (const float*)d_in[3], Wt);
  qkv<<<1024, 128, 0, stream>>>(data, Wt, arena);
  attn<<<dim3(32, 8), 256, 0, stream>>>(arena, (float*)d_out);
}